// Round 16
// baseline (198.277 us; speedup 1.0000x reference)
//
#include <hip/hip_runtime.h>
#include <math.h>

#define N_ROWS 32768
#define K_CODES 8192
#define DIM 64
#define CHUNKS 8
#define CPC (K_CODES / CHUNKS)   // 1024 codes per chunk
#define TILES (CPC / 32)         // 32 tiles of 32 codes
#define POST_BLOCKS (N_ROWS / 64)  // 512

using half8  = __attribute__((ext_vector_type(8))) _Float16;
using f32x16 = __attribute__((ext_vector_type(16))) float;

// ---------------- ws layout ----------------
#define WS_W2     0          // float w2g[8192]            32 KB
#define WS_COUNTS 32768      // int counts[8192]           32 KB
#define WS_CSUM   65536      // float csum                 4 B
#define WS_DONE   65540      // int done                   4 B (+pad)
#define WS_BEST   65552      // u64 best[32768]            256 KB
#define WS_WHL    327696     // _Float16 whl[8192][128]    2 MB (hi[64]|lo[64])

__device__ __forceinline__ void gload_lds16(const _Float16* g, _Float16* l) {
    __builtin_amdgcn_global_load_lds(
        (const __attribute__((address_space(1))) void*)g,
        (__attribute__((address_space(3))) void*)l, 16, 0, 0);
}

// ---------------- kernel 1: W hi/lo split + w2 + init ----------------
__global__ __launch_bounds__(256) void vq_prep(const float* __restrict__ W,
                                               _Float16* __restrict__ whl,
                                               float* __restrict__ w2g,
                                               unsigned long long* __restrict__ best,
                                               int* __restrict__ counts,
                                               float* __restrict__ csum,
                                               int* __restrict__ done) {
    int g = blockIdx.x * 256 + threadIdx.x;   // 0 .. 524287
    int code = g >> 6, k = g & 63;
    float w = W[g];
    _Float16 h  = (_Float16)w;
    _Float16 lo = (_Float16)(w - (float)h);
    whl[(size_t)code * 128 + k]      = h;
    whl[(size_t)code * 128 + 64 + k] = lo;
    float s = w * w;
    #pragma unroll
    for (int off = 32; off; off >>= 1) s += __shfl_down(s, off);
    if (k == 0) w2g[code] = s;
    if (g < N_ROWS)  best[g] = ~0ULL;
    if (g < K_CODES) counts[g] = 0;
    if (g == 0) { *csum = 0.f; *done = 0; }
}

// ---------------- kernel 2: MFMA scores + per-row argmin (R15 body, CHUNKS=8) ----------------
// 512 thr = 8 waves share one staged 8KB tile; ~68 live regs -> 3 blocks/CU.
__global__ __launch_bounds__(512, 4) void vq_mfma(const float* __restrict__ x,
                                                  const _Float16* __restrict__ whl,
                                                  const float* __restrict__ w2g,
                                                  unsigned long long* __restrict__ best) {
    __shared__ __align__(16) _Float16 lds[2][4096];   // 2 x 8KB

    const int t     = threadIdx.x;
    const int wv    = t >> 6;                 // 0..7
    const int l     = t & 63;
    const int ln31  = l & 31;
    const int lhalf = l >> 5;
    const int chunk = blockIdx.x & (CHUNKS - 1);
    const int rblk  = blockIdx.x / CHUNKS;
    const int rowb  = rblk * 256 + wv * 32;   // 8 waves x 32 rows = 256 rows/block
    const int cbase = chunk * CPC;

    // A fragments: exact f16 hi/lo split of this lane's row slice
    half8 ahi[4], alo[4];
    {
        const float* xr = x + (size_t)(rowb + ln31) * DIM + lhalf * 8;
        #pragma unroll
        for (int kt = 0; kt < 4; ++kt) {
            float4 a0 = *(const float4*)(xr + kt * 16);
            float4 a1 = *(const float4*)(xr + kt * 16 + 4);
            float fa[8] = {a0.x, a0.y, a0.z, a0.w, a1.x, a1.y, a1.z, a1.w};
            #pragma unroll
            for (int j = 0; j < 8; ++j) {
                _Float16 h = (_Float16)fa[j];
                ahi[kt][j] = h;
                alo[kt][j] = (_Float16)(fa[j] - (float)h);
            }
        }
    }

    // staging: thread t stages granule G=t (16B); slice from q=wv.
    const _Float16* srcp = whl + (size_t)(cbase + ln31) * 128
                               + ((wv & 1) * 8 + lhalf + 2 * (wv >> 1)) * 8;
    const int ldsG = wv * 512;   // halves; wave-uniform base (HW adds lane*16B)

    float bv[16];
    int   bi[16];
    #pragma unroll
    for (int s2 = 0; s2 < 16; ++s2) { bv[s2] = 3.4e38f; bi[s2] = 0; }

    // prologue: stage tile 0 into buf 0 (1 gload per thread)
    gload_lds16(srcp, &lds[0][0] + ldsG);
    __syncthreads();

    const float* w2p = w2g + cbase + ln31;
    int cur = 0;

    for (int tile = 0; tile < TILES; ++tile) {
        if (tile < TILES - 1)
            gload_lds16(srcp + (size_t)(tile + 1) * 4096,
                        &lds[0][0] + (cur ^ 1) * 4096 + ldsG);
        const float w2v = w2p[tile * 32];
        const _Float16* lb = &lds[0][0] + cur * 4096;

        f32x16 acc = {};
        __builtin_amdgcn_s_setprio(1);
        #pragma unroll
        for (int kt = 0; kt < 4; ++kt) {
            half8 bh = *(const half8*)(lb + ((kt * 2 + 0) * 64 + l) * 8);
            half8 bl = *(const half8*)(lb + ((kt * 2 + 1) * 64 + l) * 8);
            acc = __builtin_amdgcn_mfma_f32_32x32x16_f16(ahi[kt], bh, acc, 0, 0, 0);
            acc = __builtin_amdgcn_mfma_f32_32x32x16_f16(alo[kt], bh, acc, 0, 0, 0);
            acc = __builtin_amdgcn_mfma_f32_32x32x16_f16(ahi[kt], bl, acc, 0, 0, 0);
        }
        __builtin_amdgcn_s_setprio(0);

        const int cc = cbase + tile * 32 + ln31;
        #pragma unroll
        for (int s2 = 0; s2 < 16; ++s2) {
            float sA = fmaf(-2.f, acc[s2], w2v);
            if (sA < bv[s2]) { bv[s2] = sA; bi[s2] = cc; }
        }
        __syncthreads();
        cur ^= 1;
    }

    // per-row reduce across the 32 lanes sharing each row, then global merge
    #pragma unroll
    for (int s2 = 0; s2 < 16; ++s2) {
        unsigned uk = __float_as_uint(bv[s2]);
        uk = (uk >> 31) ? ~uk : (uk | 0x80000000u);   // monotone float->uint
        unsigned long long key = ((unsigned long long)uk << 32) | (unsigned)bi[s2];
        #pragma unroll
        for (int off = 16; off; off >>= 1) {
            unsigned long long o = __shfl_xor(key, off);
            key = (o < key) ? o : key;
        }
        if (ln31 == 0) {
            int rl = (s2 & 3) + 8 * (s2 >> 2) + 4 * lhalf;   // C/D row map (m74/m101)
            atomicMin(&best[rowb + rl], key);
        }
    }
}

// ---------------- kernel 3: gather z + commitment + histogram + ticketed finalize ----------------
__global__ __launch_bounds__(256) void vq_post(const float* __restrict__ W,
                                               const float* __restrict__ x,
                                               const unsigned long long* __restrict__ best,
                                               float* __restrict__ zout,
                                               int* __restrict__ counts,
                                               float* __restrict__ csum,
                                               int* __restrict__ done,
                                               float* __restrict__ out3) {
    __shared__ float sh[4];
    __shared__ int sh_done;
    int t   = threadIdx.x;
    int row = blockIdx.x * 64 + (t >> 2);
    int seg = t & 3;
    unsigned long long key = best[row];
    int idx = (int)(key & 0xFFFFFFFFULL);
    if (seg == 0) atomicAdd(&counts[idx], 1);

    const float* wrow = W    + (size_t)idx * DIM + seg * 16;
    const float* xrow = x    + (size_t)row * DIM + seg * 16;
    float*       zrow = zout + (size_t)row * DIM + seg * 16;
    float local = 0.f;
    #pragma unroll
    for (int j = 0; j < 16; j += 4) {
        float4 wv = *(const float4*)(wrow + j);
        float4 xv = *(const float4*)(xrow + j);
        *(float4*)(zrow + j) = wv;
        float dx = wv.x - xv.x, dy = wv.y - xv.y, dz = wv.z - xv.z, dw = wv.w - xv.w;
        local += dx * dx + dy * dy + dz * dz + dw * dw;
    }
    #pragma unroll
    for (int off = 32; off; off >>= 1) local += __shfl_down(local, off);
    if ((t & 63) == 0) atomicAdd(csum, local);

    // ticket: last block computes entropy + writes scalars (R14-proven pattern)
    __threadfence();
    __syncthreads();
    if (t == 0) sh_done = atomicAdd(done, 1);
    __syncthreads();
    if (sh_done == POST_BLOCKS - 1) {
        float e = 0.f;
        for (int i = t; i < K_CODES; i += 256) {
            float c = (float)atomicAdd(&counts[i], 0);   // coherent read
            float p = c * (1.0f / N_ROWS);
            e += p * logf(p + 1e-10f);
        }
        #pragma unroll
        for (int off = 32; off; off >>= 1) e += __shfl_down(e, off);
        if ((t & 63) == 0) sh[t >> 6] = e;
        __syncthreads();
        if (t == 0) {
            float etot = sh[0] + sh[1] + sh[2] + sh[3];
            float cs   = atomicAdd(csum, 0.f);           // coherent read
            out3[0] = 0.f;
            out3[1] = cs * (1.0f / ((float)N_ROWS * DIM));
            out3[2] = expf(-etot);
        }
    }
}

extern "C" void kernel_launch(void* const* d_in, const int* in_sizes, int n_in,
                              void* d_out, int out_size, void* d_ws, size_t ws_size,
                              hipStream_t stream) {
    (void)in_sizes; (void)n_in; (void)out_size; (void)ws_size;
    const float* x = (const float*)d_in[0];
    const float* W = (const float*)d_in[1];
    float* zout = (float*)d_out;
    float* out3 = (float*)d_out + (size_t)N_ROWS * DIM;

    float*              w2g    = (float*)((char*)d_ws + WS_W2);
    int*                counts = (int*)((char*)d_ws + WS_COUNTS);
    float*              csum   = (float*)((char*)d_ws + WS_CSUM);
    int*                done   = (int*)((char*)d_ws + WS_DONE);
    unsigned long long* best   = (unsigned long long*)((char*)d_ws + WS_BEST);
    _Float16*           whl    = (_Float16*)((char*)d_ws + WS_WHL);

    vq_prep<<<K_CODES * DIM / 256,       256, 0, stream>>>(W, whl, w2g, best, counts, csum, done);
    vq_mfma<<<(N_ROWS / 256) * CHUNKS,   512, 0, stream>>>(x, whl, w2g, best);
    vq_post<<<POST_BLOCKS,               256, 0, stream>>>(W, x, best, zout, counts, csum, done, out3);
}

// Round 17
// 151.615 us; speedup vs baseline: 1.3078x; 1.3078x over previous
//
#include <hip/hip_runtime.h>
#include <math.h>

#define N_ROWS 32768
#define K_CODES 8192
#define DIM 64
#define CHUNKS 4
#define CPC (K_CODES / CHUNKS)   // 2048 codes per chunk
#define TILES (CPC / 32)         // 64 tiles of 32 codes
#define POST_BLOCKS (N_ROWS / 64)  // 512

using half8  = __attribute__((ext_vector_type(8))) _Float16;
using f32x16 = __attribute__((ext_vector_type(16))) float;

// ---------------- ws layout ----------------
#define WS_W2     0          // float w2g[8192]            32 KB
#define WS_COUNTS 32768      // int counts[8192]           32 KB
#define WS_CSUM   65536      // float csum                 4 B
#define WS_DONE   65540      // int done                   4 B (+pad)
#define WS_BEST   65552      // u64 best[32768]            256 KB
#define WS_X2     327696     // float x2g[32768]           128 KB
#define WS_WHL    458768     // _Float16 whl[8192][128]    2 MB (hi[64]|lo[64])

__device__ __forceinline__ void gload_lds16(const _Float16* g, _Float16* l) {
    __builtin_amdgcn_global_load_lds(
        (const __attribute__((address_space(1))) void*)g,
        (__attribute__((address_space(3))) void*)l, 16, 0, 0);
}

// ---------------- kernel 1: W hi/lo split + w2 + x2 + init (R15-proven) ----------------
__global__ __launch_bounds__(256) void vq_prep(const float* __restrict__ W,
                                               const float* __restrict__ x,
                                               _Float16* __restrict__ whl,
                                               float* __restrict__ w2g,
                                               float* __restrict__ x2g,
                                               unsigned long long* __restrict__ best,
                                               int* __restrict__ counts,
                                               float* __restrict__ csum,
                                               int* __restrict__ done) {
    int g = blockIdx.x * 256 + threadIdx.x;   // 0 .. 524287
    int code = g >> 6, k = g & 63;
    float w = W[g];
    _Float16 h  = (_Float16)w;
    _Float16 lo = (_Float16)(w - (float)h);
    whl[(size_t)code * 128 + k]      = h;
    whl[(size_t)code * 128 + 64 + k] = lo;
    float s = w * w;
    #pragma unroll
    for (int off = 32; off; off >>= 1) s += __shfl_down(s, off);
    if (k == 0) w2g[code] = s;
    // x2: thread g owns x[4g..4g+3]; 16 lanes per row
    float4 xv = *(const float4*)(x + (size_t)g * 4);
    float ss = xv.x * xv.x + xv.y * xv.y + xv.z * xv.z + xv.w * xv.w;
    #pragma unroll
    for (int off = 8; off; off >>= 1) ss += __shfl_down(ss, off);
    if ((g & 15) == 0) x2g[g >> 4] = ss;
    if (g < N_ROWS)  best[g] = ~0ULL;
    if (g < K_CODES) counts[g] = 0;
    if (g == 0) { *csum = 0.f; *done = 0; }
}

// ---------------- kernel 2: MFMA scores + per-row argmin (R15 byte-for-byte) ----------------
// 512 thr = 8 waves share one staged 8KB tile (2x intensity per staged byte).
__global__ __launch_bounds__(512, 4) void vq_mfma(const float* __restrict__ x,
                                                  const _Float16* __restrict__ whl,
                                                  const float* __restrict__ w2g,
                                                  unsigned long long* __restrict__ best) {
    __shared__ __align__(16) _Float16 lds[2][4096];   // 2 x 8KB

    const int t     = threadIdx.x;
    const int wv    = t >> 6;                 // 0..7
    const int l     = t & 63;
    const int ln31  = l & 31;
    const int lhalf = l >> 5;
    const int chunk = blockIdx.x & (CHUNKS - 1);
    const int rblk  = blockIdx.x / CHUNKS;
    const int rowb  = rblk * 256 + wv * 32;   // 8 waves x 32 rows = 256 rows/block
    const int cbase = chunk * CPC;

    // A fragments: exact f16 hi/lo split of this lane's row slice
    half8 ahi[4], alo[4];
    {
        const float* xr = x + (size_t)(rowb + ln31) * DIM + lhalf * 8;
        #pragma unroll
        for (int kt = 0; kt < 4; ++kt) {
            float4 a0 = *(const float4*)(xr + kt * 16);
            float4 a1 = *(const float4*)(xr + kt * 16 + 4);
            float fa[8] = {a0.x, a0.y, a0.z, a0.w, a1.x, a1.y, a1.z, a1.w};
            #pragma unroll
            for (int j = 0; j < 8; ++j) {
                _Float16 h = (_Float16)fa[j];
                ahi[kt][j] = h;
                alo[kt][j] = (_Float16)(fa[j] - (float)h);
            }
        }
    }

    // staging: thread t stages granule G=t (16B); slice selected by q=wv.
    const _Float16* srcp = whl + (size_t)(cbase + ln31) * 128
                               + ((wv & 1) * 8 + lhalf + 2 * (wv >> 1)) * 8;
    const int ldsG = wv * 512;   // halves; wave-uniform base (HW adds lane*16B)

    float bv[16];
    int   bi[16];
    #pragma unroll
    for (int s2 = 0; s2 < 16; ++s2) { bv[s2] = 3.4e38f; bi[s2] = 0; }

    // prologue: stage tile 0 into buf 0 (1 gload per thread)
    gload_lds16(srcp, &lds[0][0] + ldsG);
    __syncthreads();

    const float* w2p = w2g + cbase + ln31;
    int cur = 0;

    for (int tile = 0; tile < TILES; ++tile) {
        if (tile < TILES - 1)
            gload_lds16(srcp + (size_t)(tile + 1) * 4096,
                        &lds[0][0] + (cur ^ 1) * 4096 + ldsG);
        const float w2v = w2p[tile * 32];
        const _Float16* lb = &lds[0][0] + cur * 4096;

        f32x16 acc = {};
        __builtin_amdgcn_s_setprio(1);
        #pragma unroll
        for (int kt = 0; kt < 4; ++kt) {
            half8 bh = *(const half8*)(lb + ((kt * 2 + 0) * 64 + l) * 8);
            half8 bl = *(const half8*)(lb + ((kt * 2 + 1) * 64 + l) * 8);
            acc = __builtin_amdgcn_mfma_f32_32x32x16_f16(ahi[kt], bh, acc, 0, 0, 0);
            acc = __builtin_amdgcn_mfma_f32_32x32x16_f16(alo[kt], bh, acc, 0, 0, 0);
            acc = __builtin_amdgcn_mfma_f32_32x32x16_f16(ahi[kt], bl, acc, 0, 0, 0);
        }
        __builtin_amdgcn_s_setprio(0);

        const int cc = cbase + tile * 32 + ln31;
        #pragma unroll
        for (int s2 = 0; s2 < 16; ++s2) {
            float sA = fmaf(-2.f, acc[s2], w2v);
            if (sA < bv[s2]) { bv[s2] = sA; bi[s2] = cc; }
        }
        __syncthreads();
        cur ^= 1;
    }

    // per-row reduce across the 32 lanes sharing each row, then global merge
    #pragma unroll
    for (int s2 = 0; s2 < 16; ++s2) {
        unsigned uk = __float_as_uint(bv[s2]);
        uk = (uk >> 31) ? ~uk : (uk | 0x80000000u);   // monotone float->uint
        unsigned long long key = ((unsigned long long)uk << 32) | (unsigned)bi[s2];
        #pragma unroll
        for (int off = 16; off; off >>= 1) {
            unsigned long long o = __shfl_xor(key, off);
            key = (o < key) ? o : key;
        }
        if (ln31 == 0) {
            int rl = (s2 & 3) + 8 * (s2 >> 2) + 4 * lhalf;   // C/D row map (m74/m101)
            atomicMin(&best[rowb + rl], key);
        }
    }
}

// ---------------- kernel 3: identity gather + histogram + ticketed finalize ----------------
// Release via s_waitcnt vmcnt(0) (drains own atomics/stores) -- NOT __threadfence
// (agent fence = L2 writeback storm; R13/R16 lesson). Atomics are L2-coherent.
__global__ __launch_bounds__(256) void vq_post(const float* __restrict__ W,
                                               const unsigned long long* __restrict__ best,
                                               const float* __restrict__ x2g,
                                               float* __restrict__ zout,
                                               int* __restrict__ counts,
                                               float* __restrict__ csum,
                                               int* __restrict__ done,
                                               float* __restrict__ out3) {
    __shared__ float sh[4];
    __shared__ int sh_done;
    int t   = threadIdx.x;
    int row = blockIdx.x * 64 + (t >> 2);
    int seg = t & 3;
    unsigned long long key = best[row];
    int idx = (int)(key & 0xFFFFFFFFULL);

    const float* wrow = W    + (size_t)idx * DIM + seg * 16;
    float*       zrow = zout + (size_t)row * DIM + seg * 16;
    #pragma unroll
    for (int j = 0; j < 16; j += 4) *(float4*)(zrow + j) = *(const float4*)(wrow + j);

    float local = 0.f;
    if (seg == 0) {
        atomicAdd(&counts[idx], 1);
        unsigned uk = (unsigned)(key >> 32);
        unsigned ob = (uk & 0x80000000u) ? (uk & 0x7FFFFFFFu) : ~uk;   // inverse monotone map
        local = x2g[row] + __uint_as_float(ob);                        // = |x-W[idx]|^2
    }
    #pragma unroll
    for (int off = 32; off; off >>= 1) local += __shfl_down(local, off);
    if ((t & 63) == 0) atomicAdd(csum, local);

    // release: drain this block's atomics/stores, then take a ticket
    asm volatile("s_waitcnt vmcnt(0)" ::: "memory");
    __syncthreads();
    if (t == 0) sh_done = atomicAdd(done, 1);
    __syncthreads();
    if (sh_done == POST_BLOCKS - 1) {   // all other blocks' atomics completed
        float e = 0.f;
        for (int i = t; i < K_CODES; i += 256) {
            float c = (float)atomicAdd(&counts[i], 0);   // atomic (coherent) read
            float p = c * (1.0f / N_ROWS);
            e += p * logf(p + 1e-10f);
        }
        #pragma unroll
        for (int off = 32; off; off >>= 1) e += __shfl_down(e, off);
        if ((t & 63) == 0) sh[t >> 6] = e;
        __syncthreads();
        if (t == 0) {
            float etot = sh[0] + sh[1] + sh[2] + sh[3];
            float cs   = atomicAdd(csum, 0.f);           // atomic (coherent) read
            out3[0] = 0.f;
            out3[1] = cs * (1.0f / ((float)N_ROWS * DIM));
            out3[2] = expf(-etot);
        }
    }
}

extern "C" void kernel_launch(void* const* d_in, const int* in_sizes, int n_in,
                              void* d_out, int out_size, void* d_ws, size_t ws_size,
                              hipStream_t stream) {
    (void)in_sizes; (void)n_in; (void)out_size; (void)ws_size;
    const float* x = (const float*)d_in[0];
    const float* W = (const float*)d_in[1];
    float* zout = (float*)d_out;
    float* out3 = (float*)d_out + (size_t)N_ROWS * DIM;

    float*              w2g    = (float*)((char*)d_ws + WS_W2);
    int*                counts = (int*)((char*)d_ws + WS_COUNTS);
    float*              csum   = (float*)((char*)d_ws + WS_CSUM);
    int*                done   = (int*)((char*)d_ws + WS_DONE);
    unsigned long long* best   = (unsigned long long*)((char*)d_ws + WS_BEST);
    float*              x2g    = (float*)((char*)d_ws + WS_X2);
    _Float16*           whl    = (_Float16*)((char*)d_ws + WS_WHL);

    vq_prep<<<K_CODES * DIM / 256,     256, 0, stream>>>(W, x, whl, w2g, x2g, best, counts, csum, done);
    vq_mfma<<<(N_ROWS / 256) * CHUNKS, 512, 0, stream>>>(x, whl, w2g, best);
    vq_post<<<POST_BLOCKS,             256, 0, stream>>>(W, best, x2g, zout, counts, csum, done, out3);
}

// Round 18
// 138.412 us; speedup vs baseline: 1.4325x; 1.0954x over previous
//
#include <hip/hip_runtime.h>
#include <math.h>

#define N_ROWS 32768
#define K_CODES 8192
#define DIM 64
#define CHUNKS 4
#define CPC (K_CODES / CHUNKS)   // 2048 codes per chunk
#define TILES (CPC / 32)         // 64 tiles of 32 codes
#define ITERS (TILES / 2)        // 32 iterations, 2 tiles each

using half8  = __attribute__((ext_vector_type(8))) _Float16;
using f32x16 = __attribute__((ext_vector_type(16))) float;

// ---------------- ws layout ----------------
#define WS_W2     0          // float w2g[8192]            32 KB
#define WS_COUNTS 32768      // int counts[8192]           32 KB
#define WS_CSUM   65536      // float csum                 4 B
#define WS_ESUM   65540      // float esum                 4 B
#define WS_DONE   65544      // int done                   4 B (+pad)
#define WS_BEST   65552      // u64 best[32768]            256 KB
#define WS_X2     327696     // float x2g[32768]           128 KB
#define WS_WHL    458768     // _Float16 whl[8192][128]    2 MB (hi[64]|lo[64])

__device__ __forceinline__ void gload_lds16(const _Float16* g, _Float16* l) {
    __builtin_amdgcn_global_load_lds(
        (const __attribute__((address_space(1))) void*)g,
        (__attribute__((address_space(3))) void*)l, 16, 0, 0);
}

// ---------------- kernel 1: W hi/lo split + w2 + x2 + init (R15-proven) ----------------
__global__ __launch_bounds__(256) void vq_prep(const float* __restrict__ W,
                                               const float* __restrict__ x,
                                               _Float16* __restrict__ whl,
                                               float* __restrict__ w2g,
                                               float* __restrict__ x2g,
                                               unsigned long long* __restrict__ best,
                                               int* __restrict__ counts,
                                               float* __restrict__ scal,
                                               int* __restrict__ done) {
    int g = blockIdx.x * 256 + threadIdx.x;   // 0 .. 524287
    int code = g >> 6, k = g & 63;
    float w = W[g];
    _Float16 h  = (_Float16)w;
    _Float16 lo = (_Float16)(w - (float)h);
    whl[(size_t)code * 128 + k]      = h;
    whl[(size_t)code * 128 + 64 + k] = lo;
    float s = w * w;
    #pragma unroll
    for (int off = 32; off; off >>= 1) s += __shfl_down(s, off);
    if (k == 0) w2g[code] = s;
    // x2: thread g owns x[4g..4g+3]; 16 lanes per row
    float4 xv = *(const float4*)(x + (size_t)g * 4);
    float ss = xv.x * xv.x + xv.y * xv.y + xv.z * xv.z + xv.w * xv.w;
    #pragma unroll
    for (int off = 8; off; off >>= 1) ss += __shfl_down(ss, off);
    if ((g & 15) == 0) x2g[g >> 4] = ss;
    if (g < N_ROWS)  best[g] = ~0ULL;
    if (g < K_CODES) counts[g] = 0;
    if (g == 0) { scal[0] = 0.f; scal[1] = 0.f; *done = 0; }
}

// ---------------- kernel 2: MFMA scores + per-row argmin ----------------
// R15 body (512 thr, 8 waves share staged tiles) + 2 tiles per barrier:
// 32 barriers instead of 64, two independent MFMA chains per iteration.
__global__ __launch_bounds__(512, 4) void vq_mfma(const float* __restrict__ x,
                                                  const _Float16* __restrict__ whl,
                                                  const float* __restrict__ w2g,
                                                  unsigned long long* __restrict__ best) {
    __shared__ __align__(16) _Float16 lds[4][4096];   // 4 x 8KB tile buffers

    const int t     = threadIdx.x;
    const int wv    = t >> 6;                 // 0..7
    const int l     = t & 63;
    const int ln31  = l & 31;
    const int lhalf = l >> 5;
    const int chunk = blockIdx.x & (CHUNKS - 1);
    const int rblk  = blockIdx.x / CHUNKS;
    const int rowb  = rblk * 256 + wv * 32;   // 8 waves x 32 rows = 256 rows/block
    const int cbase = chunk * CPC;

    // A fragments: exact f16 hi/lo split of this lane's row slice
    half8 ahi[4], alo[4];
    {
        const float* xr = x + (size_t)(rowb + ln31) * DIM + lhalf * 8;
        #pragma unroll
        for (int kt = 0; kt < 4; ++kt) {
            float4 a0 = *(const float4*)(xr + kt * 16);
            float4 a1 = *(const float4*)(xr + kt * 16 + 4);
            float fa[8] = {a0.x, a0.y, a0.z, a0.w, a1.x, a1.y, a1.z, a1.w};
            #pragma unroll
            for (int j = 0; j < 8; ++j) {
                _Float16 h = (_Float16)fa[j];
                ahi[kt][j] = h;
                alo[kt][j] = (_Float16)(fa[j] - (float)h);
            }
        }
    }

    // staging: thread t stages granule G=t (16B) of a tile; slice from q=wv.
    const _Float16* srcp = whl + (size_t)(cbase + ln31) * 128
                               + ((wv & 1) * 8 + lhalf + 2 * (wv >> 1)) * 8;
    const int ldsG = wv * 512;   // halves; wave-uniform base (HW adds lane*16B)

    float bv[16];
    int   bi[16];
    #pragma unroll
    for (int s2 = 0; s2 < 16; ++s2) { bv[s2] = 3.4e38f; bi[s2] = 0; }

    // prologue: stage tiles 0,1
    gload_lds16(srcp,        &lds[0][0] + ldsG);
    gload_lds16(srcp + 4096, &lds[1][0] + ldsG);
    __syncthreads();

    const float* w2p = w2g + cbase + ln31;

    for (int it = 0; it < ITERS; ++it) {
        const int tA = 2 * it, tB = 2 * it + 1;
        if (it < ITERS - 1) {
            gload_lds16(srcp + (size_t)(tA + 2) * 4096, &lds[(tA + 2) & 3][0] + ldsG);
            gload_lds16(srcp + (size_t)(tB + 2) * 4096, &lds[(tB + 2) & 3][0] + ldsG);
        }
        const float w2A = w2p[tA * 32];
        const float w2B = w2p[tB * 32];
        const _Float16* lbA = &lds[tA & 3][0];
        const _Float16* lbB = &lds[tB & 3][0];

        f32x16 accA = {}, accB = {};          // independent chains (ILP)
        __builtin_amdgcn_s_setprio(1);
        #pragma unroll
        for (int kt = 0; kt < 4; ++kt) {
            half8 bhA = *(const half8*)(lbA + ((kt * 2 + 0) * 64 + l) * 8);
            half8 blA = *(const half8*)(lbA + ((kt * 2 + 1) * 64 + l) * 8);
            half8 bhB = *(const half8*)(lbB + ((kt * 2 + 0) * 64 + l) * 8);
            half8 blB = *(const half8*)(lbB + ((kt * 2 + 1) * 64 + l) * 8);
            accA = __builtin_amdgcn_mfma_f32_32x32x16_f16(ahi[kt], bhA, accA, 0, 0, 0);
            accB = __builtin_amdgcn_mfma_f32_32x32x16_f16(ahi[kt], bhB, accB, 0, 0, 0);
            accA = __builtin_amdgcn_mfma_f32_32x32x16_f16(alo[kt], bhA, accA, 0, 0, 0);
            accB = __builtin_amdgcn_mfma_f32_32x32x16_f16(alo[kt], bhB, accB, 0, 0, 0);
            accA = __builtin_amdgcn_mfma_f32_32x32x16_f16(ahi[kt], blA, accA, 0, 0, 0);
            accB = __builtin_amdgcn_mfma_f32_32x32x16_f16(ahi[kt], blB, accB, 0, 0, 0);
        }
        __builtin_amdgcn_s_setprio(0);

        const int ccA = cbase + tA * 32 + ln31;
        const int ccB = cbase + tB * 32 + ln31;
        #pragma unroll
        for (int s2 = 0; s2 < 16; ++s2) {
            float sA = fmaf(-2.f, accA[s2], w2A);
            float sB = fmaf(-2.f, accB[s2], w2B);
            if (sA < bv[s2]) { bv[s2] = sA; bi[s2] = ccA; }
            if (sB < bv[s2]) { bv[s2] = sB; bi[s2] = ccB; }
        }
        __syncthreads();   // reads of tA,tB done; staged tA+2,tB+2 drained
    }

    // per-row reduce across the 32 lanes sharing each row, then global merge
    #pragma unroll
    for (int s2 = 0; s2 < 16; ++s2) {
        unsigned uk = __float_as_uint(bv[s2]);
        uk = (uk >> 31) ? ~uk : (uk | 0x80000000u);   // monotone float->uint
        unsigned long long key = ((unsigned long long)uk << 32) | (unsigned)bi[s2];
        #pragma unroll
        for (int off = 16; off; off >>= 1) {
            unsigned long long o = __shfl_xor(key, off);
            key = (o < key) ? o : key;
        }
        if (ln31 == 0) {
            int rl = (s2 & 3) + 8 * (s2 >> 2) + 4 * lhalf;   // C/D row map (m74/m101)
            atomicMin(&best[rowb + rl], key);
        }
    }
}

// ---------------- kernel 3: gather z + histogram + commitment (identity, R15) ----------------
__global__ __launch_bounds__(256) void vq_gather(const float* __restrict__ W,
                                                 const unsigned long long* __restrict__ best,
                                                 const float* __restrict__ x2g,
                                                 float* __restrict__ zout,
                                                 int* __restrict__ counts,
                                                 float* __restrict__ csum) {
    int t   = threadIdx.x;
    int row = blockIdx.x * 64 + (t >> 2);
    int seg = t & 3;
    unsigned long long key = best[row];
    int idx = (int)(key & 0xFFFFFFFFULL);

    const float* wrow = W    + (size_t)idx * DIM + seg * 16;
    float*       zrow = zout + (size_t)row * DIM + seg * 16;
    #pragma unroll
    for (int j = 0; j < 16; j += 4) *(float4*)(zrow + j) = *(const float4*)(wrow + j);

    float local = 0.f;
    if (seg == 0) {
        atomicAdd(&counts[idx], 1);
        unsigned uk = (unsigned)(key >> 32);
        unsigned ob = (uk & 0x80000000u) ? (uk & 0x7FFFFFFFu) : ~uk;   // inverse monotone map
        local = x2g[row] + __uint_as_float(ob);                        // = |x-W[idx]|^2
    }
    #pragma unroll
    for (int off = 32; off; off >>= 1) local += __shfl_down(local, off);
    if ((t & 63) == 0) atomicAdd(csum, local);
}

// ---------------- kernel 4: entropy (32 blocks) + last-block finalize (R15) ----------------
__global__ __launch_bounds__(256) void vq_final(const int* __restrict__ counts,
                                                float* __restrict__ scal,   // [csum, esum]
                                                int* __restrict__ done,
                                                float* __restrict__ out3) {
    __shared__ float sh[4];
    int g = blockIdx.x * 256 + threadIdx.x;   // 8192 threads total
    float p = (float)counts[g] * (1.0f / N_ROWS);
    float e = p * logf(p + 1e-10f);
    #pragma unroll
    for (int off = 32; off; off >>= 1) e += __shfl_down(e, off);
    if ((threadIdx.x & 63) == 0) sh[threadIdx.x >> 6] = e;
    __syncthreads();
    if (threadIdx.x == 0) {
        atomicAdd(&scal[1], sh[0] + sh[1] + sh[2] + sh[3]);
        __threadfence();
        int old = atomicAdd(done, 1);
        if (old == 31) {
            float es = atomicAdd(&scal[1], 0.f);
            float cs = atomicAdd(&scal[0], 0.f);
            out3[0] = 0.f;
            out3[1] = cs * (1.0f / ((float)N_ROWS * DIM));
            out3[2] = expf(-es);
        }
    }
}

extern "C" void kernel_launch(void* const* d_in, const int* in_sizes, int n_in,
                              void* d_out, int out_size, void* d_ws, size_t ws_size,
                              hipStream_t stream) {
    (void)in_sizes; (void)n_in; (void)out_size; (void)ws_size;
    const float* x = (const float*)d_in[0];
    const float* W = (const float*)d_in[1];
    float* zout = (float*)d_out;
    float* out3 = (float*)d_out + (size_t)N_ROWS * DIM;

    float*              w2g    = (float*)((char*)d_ws + WS_W2);
    int*                counts = (int*)((char*)d_ws + WS_COUNTS);
    float*              scal   = (float*)((char*)d_ws + WS_CSUM);   // [csum, esum]
    int*                done   = (int*)((char*)d_ws + WS_DONE);
    unsigned long long* best   = (unsigned long long*)((char*)d_ws + WS_BEST);
    float*              x2g    = (float*)((char*)d_ws + WS_X2);
    _Float16*           whl    = (_Float16*)((char*)d_ws + WS_WHL);

    vq_prep  <<<K_CODES * DIM / 256,     256, 0, stream>>>(W, x, whl, w2g, x2g, best, counts, scal, done);
    vq_mfma  <<<(N_ROWS / 256) * CHUNKS, 512, 0, stream>>>(x, whl, w2g, best);
    vq_gather<<<N_ROWS / 64,             256, 0, stream>>>(W, best, x2g, zout, counts, &scal[0]);
    vq_final <<<K_CODES / 256,           256, 0, stream>>>(counts, scal, done, out3);
}